// Round 7
// baseline (27516.675 us; speedup 1.0000x reference)
//
#include <hip/hip_runtime.h>
#include <hip/hip_bf16.h>

#define S_LEN 4096
#define EDIM  300
#define HDIM  512
#define G4    2048
#define NTAG  5
#define NEGV  -10000.0f
#define START_TAG 3
#define STOP_TAG  4
#define L2E 1.4426950408889634f
#define LN2 0.6931471805599453f
#define POIS_U 0x7F7F7F7Fu
#define HP_ROW 512   // bf16 elements per (dir,step) h row

typedef __attribute__((ext_vector_type(4))) float f32x4;
typedef __attribute__((ext_vector_type(4))) unsigned int u32x4;
typedef __attribute__((ext_vector_type(2))) unsigned int u32x2;

// ---------- workspace layout (bytes) ----------
static constexpr size_t OFF_XP    = 0;                                   // bf16 [2][S][2048]
static constexpr size_t XP_BYTES  = (size_t)2 * S_LEN * G4 * 2;
static constexpr size_t OFF_HBS   = OFF_XP + XP_BYTES;                   // bf16 [2][S][512] h publication
static constexpr size_t HBS_BYTES = (size_t)2 * S_LEN * HDIM * 4;       // region reserved (f32-era size)
static constexpr size_t OFF_FEATS = OFF_HBS + HBS_BYTES;                 // f32 [S][5]
static constexpr size_t OFF_MPART = OFF_FEATS + (size_t)S_LEN * NTAG * 4;// f32 [64][25]
static constexpr size_t OFF_GOLD  = OFF_MPART + (size_t)64 * 25 * 4;     // f32 [64]
static constexpr size_t WS_NEEDED = OFF_GOLD + 256;

// ---------- helpers ----------
static __device__ __forceinline__ float fexp_(float x){ return __builtin_amdgcn_exp2f(x * L2E); }
static __device__ __forceinline__ float fsig_(float x){ return __builtin_amdgcn_rcpf(1.0f + fexp_(-x)); }
static __device__ __forceinline__ float ftanh_(float x){ return 1.0f - 2.0f*__builtin_amdgcn_rcpf(fexp_(2.0f*x) + 1.0f); }

static __device__ __forceinline__ float lse5(float t0,float t1,float t2,float t3,float t4){
  float m = fmaxf(fmaxf(fmaxf(t0,t1),fmaxf(t2,t3)),t4);
  float s = __builtin_amdgcn_exp2f((t0-m)*L2E) + __builtin_amdgcn_exp2f((t1-m)*L2E)
          + __builtin_amdgcn_exp2f((t2-m)*L2E) + __builtin_amdgcn_exp2f((t3-m)*L2E)
          + __builtin_amdgcn_exp2f((t4-m)*L2E);
  return m + __builtin_amdgcn_logf(s)*LN2;
}

// C[i][j] = LSE_k(cur[i][k] + bv[k][j]); lane layout: lane = i*5+j (lanes 0..24)
static __device__ __forceinline__ float lse_mm(float cur, float bv, int i, int j){
  const float a0=__shfl(cur, i*5+0), a1=__shfl(cur, i*5+1), a2=__shfl(cur, i*5+2),
              a3=__shfl(cur, i*5+3), a4=__shfl(cur, i*5+4);
  const float c0=__shfl(bv, 0+j),  c1=__shfl(bv, 5+j),  c2=__shfl(bv, 10+j),
              c3=__shfl(bv, 15+j), c4=__shfl(bv, 20+j);
  return lse5(a0+c0, a1+c1, a2+c2, a3+c3, a4+c4);
}

// ---------- phase 0: poison-fill h publication buffer (coherent stores) ----------
__global__ __launch_bounds__(256) void fill_poison(float* __restrict__ p, int n4){
  const int idx = blockIdx.x*blockDim.x + threadIdx.x;
  const int stride = gridDim.x*blockDim.x;
  f32x4 pv;
  pv.x = __uint_as_float(POIS_U); pv.y = __uint_as_float(POIS_U);
  pv.z = __uint_as_float(POIS_U); pv.w = __uint_as_float(POIS_U);
  for (int i = idx; i < n4; i += stride) {
    float* dst = p + (size_t)i*4;
    asm volatile("global_store_dwordx4 %0, %1, off sc0 sc1" :: "v"(dst), "v"(pv) : "memory");
  }
}

// ---------- phase A: xp[dir][s][2048] = emb[sent[s]] @ w_ih.T + (b_ih+b_hh), stored bf16 ----------
__global__ __launch_bounds__(256) void xp_gemm(
    const int* __restrict__ sentence, const float* __restrict__ emb,
    const float* __restrict__ w_ih_f, const float* __restrict__ b_ih_f, const float* __restrict__ b_hh_f,
    const float* __restrict__ w_ih_b, const float* __restrict__ b_ih_b, const float* __restrict__ b_hh_b,
    __hip_bfloat16* __restrict__ xp)
{
  __shared__ float At[32][132];
  __shared__ float Bt[32][132];
  __shared__ int sent_s[128];

  const int dir = blockIdx.y;
  const int tm = blockIdx.x & 31;
  const int tn = blockIdx.x >> 5;
  const float* __restrict__ wih = dir ? w_ih_b : w_ih_f;
  const float* __restrict__ bi  = dir ? b_ih_b : b_ih_f;
  const float* __restrict__ bh  = dir ? b_hh_b : b_hh_f;

  const int tid = threadIdx.x;
  if (tid < 128) sent_s[tid] = sentence[tm*128 + tid];

  const int ty = tid >> 4, tx = tid & 15;
  const int li = tid >> 1, lh = tid & 1;

  float acc[8][8];
#pragma unroll
  for (int i = 0; i < 8; ++i){
#pragma unroll
    for (int j = 0; j < 8; ++j) acc[i][j] = 0.0f;
  }
  __syncthreads();

  for (int kc0 = 0; kc0 < EDIM; kc0 += 32) {
    const int kw = (EDIM - kc0 < 32) ? (EDIM - kc0) : 32;
    if (kc0 + lh*16 + 16 <= EDIM) {
      const float4* pa = (const float4*)(emb + (size_t)sent_s[li]*EDIM + kc0 + lh*16);
      const float4* pb = (const float4*)(wih + (size_t)(tn*128 + li)*EDIM + kc0 + lh*16);
#pragma unroll
      for (int v = 0; v < 4; ++v) {
        const float4 a = pa[v], b = pb[v];
        const int kk = lh*16 + v*4;
        At[kk+0][li] = a.x; At[kk+1][li] = a.y; At[kk+2][li] = a.z; At[kk+3][li] = a.w;
        Bt[kk+0][li] = b.x; Bt[kk+1][li] = b.y; Bt[kk+2][li] = b.z; Bt[kk+3][li] = b.w;
      }
    } else {
#pragma unroll
      for (int jj = 0; jj < 16; ++jj) {
        const int col = kc0 + lh*16 + jj;
        float av = 0.f, bv = 0.f;
        if (col < EDIM) {
          av = emb[(size_t)sent_s[li]*EDIM + col];
          bv = wih[(size_t)(tn*128 + li)*EDIM + col];
        }
        At[lh*16+jj][li] = av;
        Bt[lh*16+jj][li] = bv;
      }
    }
    __syncthreads();
#pragma unroll 4
    for (int k = 0; k < kw; ++k) {
      const float4 a0 = *(const float4*)&At[k][ty*8];
      const float4 a1 = *(const float4*)&At[k][ty*8+4];
      const float4 b0 = *(const float4*)&Bt[k][tx*8];
      const float4 b1 = *(const float4*)&Bt[k][tx*8+4];
      const float av[8] = {a0.x,a0.y,a0.z,a0.w,a1.x,a1.y,a1.z,a1.w};
      const float bv[8] = {b0.x,b0.y,b0.z,b0.w,b1.x,b1.y,b1.z,b1.w};
#pragma unroll
      for (int i = 0; i < 8; ++i){
#pragma unroll
        for (int j = 0; j < 8; ++j) acc[i][j] = __builtin_fmaf(av[i], bv[j], acc[i][j]);
      }
    }
    __syncthreads();
  }

  const int n0 = tn*128 + tx*8;
  float bias[8];
#pragma unroll
  for (int j = 0; j < 8; ++j) bias[j] = bi[n0+j] + bh[n0+j];

  __hip_bfloat16* __restrict__ xpd = xp + (size_t)dir * S_LEN * G4;
#pragma unroll
  for (int i = 0; i < 8; ++i) {
    const int m = tm*128 + ty*8 + i;
    __hip_bfloat16 __align__(16) tmp[8];
#pragma unroll
    for (int j = 0; j < 8; ++j) tmp[j] = __float2bfloat16(acc[i][j] + bias[j]);
    *(uint4*)(xpd + (size_t)m*G4 + n0) = *(const uint4*)tmp;
  }
}

// ---------- phase B: persistent BiLSTM — bf16 W in LDS, dual-scope store/poll ----------
// 256 blocks; b%8==0 -> forward role b>>3, b%8==1 -> backward, others exit (roles are a pure
// function of blockIdx -> coverage guaranteed). If blockIdx%8 == XCD (empirical round-robin),
// each direction is XCD-pure and the sc0 fast path resolves in the shared local L2; otherwise
// the sc0sc1 path (IF$) guarantees progress. Producers dual-store; consumers dual-poll.
// Per wg: 16 units, W slice 64 rows x 512 cols bf16 in 64 KB LDS. 4 waves x 4 units,
// R2-verified acc[16] reduce-scatter + gate core. No barriers in the step loop.
__global__ __launch_bounds__(256, 1) void lstm_pers(
    const float* __restrict__ w_hh_f, const float* __restrict__ w_hh_b,
    const __hip_bfloat16* __restrict__ xp, unsigned short* __restrict__ hpub)
{
  extern __shared__ unsigned int Wl[];   // [64][256] u32 = 64 rows x 512 bf16 = 64 KB

  const int b = blockIdx.x;
  const int slot = b & 7;
  if (slot >= 2) return;                 // 192 loser blocks exit immediately
  const int dir  = slot;
  const int role = b >> 3;               // 0..31

  const int tid = threadIdx.x;
  const int w_  = tid >> 6;              // wave 0..3
  const int l   = tid & 63;
  const int u   = l & 3;                 // unit tracked by this lane's gate path
  const int gu  = role*16 + w_*4 + u;    // global unit

  const float* __restrict__ whh = dir ? w_hh_b : w_hh_f;
  const __hip_bfloat16* __restrict__ xpd = xp + (size_t)dir * S_LEN * G4;
  unsigned short* __restrict__ hp = hpub + (size_t)dir * S_LEN * HP_ROW;

  // ---- stage W slice to LDS as bf16. LDS row R = wv*16 + ul*4 + g  <- whh row g*HDIM + role*16 + wv*4 + ul
  {
    const int R = tid >> 2, q = tid & 3;           // thread covers row R, f32 cols [q*128, q*128+128)
    const int g = R & 3, ul = (R >> 2) & 3, wv = R >> 4;
    const float* src = whh + (size_t)(g*HDIM + role*16 + wv*4 + ul)*HDIM + q*128;
    unsigned int* dst = Wl + R*256 + q*64;         // 64 u32 = 128 bf16
#pragma unroll
    for (int k = 0; k < 128; k += 8) {
      const f32x4 f0 = *(const f32x4*)(src + k);
      const f32x4 f1 = *(const f32x4*)(src + k + 4);
      u32x4 pk;
      pk.x = (unsigned int)__builtin_bit_cast(unsigned short, __float2bfloat16(f0.x))
           | ((unsigned int)__builtin_bit_cast(unsigned short, __float2bfloat16(f0.y)) << 16);
      pk.y = (unsigned int)__builtin_bit_cast(unsigned short, __float2bfloat16(f0.z))
           | ((unsigned int)__builtin_bit_cast(unsigned short, __float2bfloat16(f0.w)) << 16);
      pk.z = (unsigned int)__builtin_bit_cast(unsigned short, __float2bfloat16(f1.x))
           | ((unsigned int)__builtin_bit_cast(unsigned short, __float2bfloat16(f1.y)) << 16);
      pk.w = (unsigned int)__builtin_bit_cast(unsigned short, __float2bfloat16(f1.z))
           | ((unsigned int)__builtin_bit_cast(unsigned short, __float2bfloat16(f1.w)) << 16);
      *(u32x4*)(dst + k/2) = pk;
    }
  }
  __syncthreads();

  const unsigned int* wrow = Wl + (size_t)(w_*16)*256 + l*4;  // row r at wrow + r*256 (u32x4 = 8 bf16 cols)

  const __hip_bfloat16* xptr = xpd + (size_t)(dir ? (S_LEN-1) : 0)*G4 + gu;
  const ptrdiff_t xstep = dir ? -(ptrdiff_t)G4 : (ptrdiff_t)G4;
  float xn0 = __bfloat162float(xptr[0*HDIM]);
  float xn1 = __bfloat162float(xptr[1*HDIM]);
  float xn2 = __bfloat162float(xptr[2*HDIM]);
  float xn3 = __bfloat162float(xptr[3*HDIM]);

  // gather lane for row r=4u+g sits at lane f_ pattern (R2-verified mapping)
  const int f_ = 2*(l&1) + ((l>>1)&1);
  float cst = 0.0f;

  // ---- step 0: h_{-1}=0, gates from xp only; publish (dual store)
  {
    const float iv = fsig_(xn0), fv = fsig_(xn1), zv = ftanh_(xn2), ov = fsig_(xn3);
    cst = iv*zv;
    const float hval = ov * ftanh_(cst);
    const unsigned int hb = (unsigned int)__builtin_bit_cast(unsigned short, __float2bfloat16(hval));
    u32x2 g2;
    g2.x = __shfl(hb, 0) | (__shfl(hb, 1) << 16);
    g2.y = __shfl(hb, 2) | (__shfl(hb, 3) << 16);
    if (l == 0) {
      unsigned short* dp = hp + (size_t)0*HP_ROW + role*16 + w_*4;
      asm volatile("global_store_dwordx2 %0, %1, off sc0"     :: "v"(dp), "v"(g2));
      asm volatile("global_store_dwordx2 %0, %1, off sc0 sc1" :: "v"(dp), "v"(g2));
    }
    xptr += xstep;
    xn0 = __bfloat162float(xptr[0*HDIM]);
    xn1 = __bfloat162float(xptr[1*HDIM]);
    xn2 = __bfloat162float(xptr[2*HDIM]);
    xn3 = __bfloat162float(xptr[3*HDIM]);
  }

#pragma clang loop unroll(disable)
  for (int s = 1; s < S_LEN; ++s) {
    // 1. dual-scope poll of h_{s-1}: lane l covers bf16 units [8l, 8l+8) = 16 B.
    //    pa (sc0): local-L2 fast path. pb (sc0 sc1): IF$ truth, immune to stale local L2.
    u32x4 pa;
    {
      const unsigned short* sp = hp + (size_t)(s-1)*HP_ROW + l*8;
      for (int it = 0; it < (1<<14); ++it) {
        u32x4 qa, qb;
        asm volatile(
          "global_load_dwordx4 %0, %2, off sc0\n\t"
          "global_load_dwordx4 %1, %2, off sc0 sc1\n\t"
          "s_waitcnt vmcnt(0)"
          : "=&v"(qa), "=&v"(qb) : "v"(sp));
        const int oka = (qa.x != POIS_U) & (qa.y != POIS_U) & (qa.z != POIS_U) & (qa.w != POIS_U);
        const int okb = (qb.x != POIS_U) & (qb.y != POIS_U) & (qb.z != POIS_U) & (qb.w != POIS_U);
        pa = oka ? qa : qb;
        if (__all(oka | okb)) break;
      }
    }

    // 2. matvec: 16 gate rows x 8 cols, W unpacked from LDS bf16
    float acc[16];
    {
      const float h0 = __uint_as_float(pa.x << 16), h1 = __uint_as_float(pa.x & 0xFFFF0000u);
      const float h2 = __uint_as_float(pa.y << 16), h3 = __uint_as_float(pa.y & 0xFFFF0000u);
      const float h4 = __uint_as_float(pa.z << 16), h5 = __uint_as_float(pa.z & 0xFFFF0000u);
      const float h6 = __uint_as_float(pa.w << 16), h7 = __uint_as_float(pa.w & 0xFFFF0000u);
#pragma unroll
      for (int r = 0; r < 16; ++r) {
        const u32x4 wv4 = *(const u32x4*)(wrow + r*256);
        float a =            __uint_as_float(wv4.x << 16)        * h0;
        a = __builtin_fmaf(__uint_as_float(wv4.x & 0xFFFF0000u), h1, a);
        a = __builtin_fmaf(__uint_as_float(wv4.y << 16),         h2, a);
        a = __builtin_fmaf(__uint_as_float(wv4.y & 0xFFFF0000u), h3, a);
        a = __builtin_fmaf(__uint_as_float(wv4.z << 16),         h4, a);
        a = __builtin_fmaf(__uint_as_float(wv4.z & 0xFFFF0000u), h5, a);
        a = __builtin_fmaf(__uint_as_float(wv4.w << 16),         h6, a);
        a = __builtin_fmaf(__uint_as_float(wv4.w & 0xFFFF0000u), h7, a);
        acc[r] = a;
      }
    }

    // 3. reduce-scatter 16 row-partials over 64 lanes (R2-verified)
#pragma unroll
    for (int k = 0; k < 4; ++k) {
      const int m = 1 << k;
      const int half = 8 >> k;
      const bool up = (l & m) != 0;
#pragma unroll
      for (int t = 0; t < half; ++t) {
        const float mine = up ? acc[half+t] : acc[t];
        const float send = up ? acc[t] : acc[half+t];
        acc[t] = mine + __shfl_xor(send, m);
      }
    }
    float tot = acc[0];
    tot += __shfl_xor(tot, 16);
    tot += __shfl_xor(tot, 32);

    // 4. gates for unit u = l&3 (all lanes redundant; R2-verified gather); publish (dual store)
    {
      const float gi = __shfl(tot, f_ + 0)  + xn0;
      const float gf = __shfl(tot, f_ + 8)  + xn1;
      const float gg = __shfl(tot, f_ + 4)  + xn2;
      const float go = __shfl(tot, f_ + 12) + xn3;
      const float iv = fsig_(gi), fv = fsig_(gf), zv = ftanh_(gg), ov = fsig_(go);
      cst = fv*cst + iv*zv;
      const float hval = ov * ftanh_(cst);
      const unsigned int hb = (unsigned int)__builtin_bit_cast(unsigned short, __float2bfloat16(hval));
      u32x2 g2;
      g2.x = __shfl(hb, 0) | (__shfl(hb, 1) << 16);
      g2.y = __shfl(hb, 2) | (__shfl(hb, 3) << 16);
      if (l == 0) {
        unsigned short* dp = hp + (size_t)s*HP_ROW + role*16 + w_*4;
        asm volatile("global_store_dwordx2 %0, %1, off sc0"     :: "v"(dp), "v"(g2));
        asm volatile("global_store_dwordx2 %0, %1, off sc0 sc1" :: "v"(dp), "v"(g2));
      }
    }

    // 5. prefetch next step's xp gate values (off the critical path)
    if (s + 1 < S_LEN) {
      xptr += xstep;
      xn0 = __bfloat162float(xptr[0*HDIM]);
      xn1 = __bfloat162float(xptr[1*HDIM]);
      xn2 = __bfloat162float(xptr[2*HDIM]);
      xn3 = __bfloat162float(xptr[3*HDIM]);
    }
  }
}

// ---------- phase C: feats[s][t] = [hf,hb] . w_tag[t] + b_tag[t] (h is bf16) ----------
__global__ __launch_bounds__(64) void feats_ker(
    const unsigned short* __restrict__ hpub, const float* __restrict__ w_tag,
    const float* __restrict__ b_tag, float* __restrict__ feats)
{
  const int row = blockIdx.x;
  const int l = threadIdx.x;
  const u32x4 hfv4 = *(const u32x4*)(hpub + (size_t)row*HP_ROW + l*8);
  const u32x4 hbv4 = *(const u32x4*)(hpub + (size_t)S_LEN*HP_ROW + (size_t)(S_LEN-1-row)*HP_ROW + l*8);
  float hf[8], hb[8];
  hf[0]=__uint_as_float(hfv4.x<<16); hf[1]=__uint_as_float(hfv4.x&0xFFFF0000u);
  hf[2]=__uint_as_float(hfv4.y<<16); hf[3]=__uint_as_float(hfv4.y&0xFFFF0000u);
  hf[4]=__uint_as_float(hfv4.z<<16); hf[5]=__uint_as_float(hfv4.z&0xFFFF0000u);
  hf[6]=__uint_as_float(hfv4.w<<16); hf[7]=__uint_as_float(hfv4.w&0xFFFF0000u);
  hb[0]=__uint_as_float(hbv4.x<<16); hb[1]=__uint_as_float(hbv4.x&0xFFFF0000u);
  hb[2]=__uint_as_float(hbv4.y<<16); hb[3]=__uint_as_float(hbv4.y&0xFFFF0000u);
  hb[4]=__uint_as_float(hbv4.z<<16); hb[5]=__uint_as_float(hbv4.z&0xFFFF0000u);
  hb[6]=__uint_as_float(hbv4.w<<16); hb[7]=__uint_as_float(hbv4.w&0xFFFF0000u);

  float a[5];
#pragma unroll
  for (int t = 0; t < 5; ++t) {
    const float* wt = w_tag + t*1024 + l*8;
    const float* wb = w_tag + t*1024 + 512 + l*8;
    float s = 0.f;
#pragma unroll
    for (int k = 0; k < 8; ++k) s = __builtin_fmaf(hf[k], wt[k], s);
#pragma unroll
    for (int k = 0; k < 8; ++k) s = __builtin_fmaf(hb[k], wb[k], s);
    a[t] = s;
  }
#pragma unroll
  for (int off = 32; off; off >>= 1) {
    a[0] += __shfl_xor(a[0], off); a[1] += __shfl_xor(a[1], off); a[2] += __shfl_xor(a[2], off);
    a[3] += __shfl_xor(a[3], off); a[4] += __shfl_xor(a[4], off);
  }
  if (l == 0) {
#pragma unroll
    for (int t = 0; t < 5; ++t) feats[row*NTAG+t] = a[t] + b_tag[t];
  }
}

// ---------- phase D: CRF log-partition + gold score ----------
__global__ __launch_bounds__(64) void crf_part(
    const float* __restrict__ feats, const float* __restrict__ trans,
    const int* __restrict__ tags, float* __restrict__ Mpart, float* __restrict__ gold_part)
{
  const int blk = blockIdx.x;
  const int l = threadIdx.x;
  const int s0 = blk * 64;
  const bool act = (l < 25);
  const int i = act ? (l/5) : 0;
  const int j = act ? (l%5) : 0;
  const float tT = trans[j*NTAG + i];
  float cur = tT + feats[(size_t)s0*NTAG + j];
  for (int s = s0+1; s < s0+64; ++s) {
    const float bv = tT + feats[(size_t)s*NTAG + j];
    cur = lse_mm(cur, bv, i, j);
  }
  if (act) Mpart[blk*25 + l] = cur;

  const int s = s0 + l;
  const int tg = tags[s];
  const int pv = (s == 0) ? START_TAG : tags[s-1];
  float gv = trans[tg*NTAG + pv] + feats[(size_t)s*NTAG + tg];
#pragma unroll
  for (int off = 32; off; off >>= 1) gv += __shfl_xor(gv, off);
  if (l == 0) gold_part[blk] = gv;
}

__global__ __launch_bounds__(64) void crf_final(
    const float* __restrict__ Mpart, const float* __restrict__ gold_part,
    const float* __restrict__ trans, const int* __restrict__ tags, float* __restrict__ out)
{
  const int l = threadIdx.x;
  const bool act = (l < 25);
  const int i = act ? (l/5) : 0;
  const int j = act ? (l%5) : 0;
  float cur = Mpart[act ? l : 0];
  for (int b = 1; b < 64; ++b) {
    const float bv = Mpart[b*25 + (act ? l : 0)];
    cur = lse_mm(cur, bv, i, j);
  }
  const float t0 = ((0==START_TAG)?0.f:NEGV) + __shfl(cur, 0*5 + j);
  const float t1 = ((1==START_TAG)?0.f:NEGV) + __shfl(cur, 1*5 + j);
  const float t2 = ((2==START_TAG)?0.f:NEGV) + __shfl(cur, 2*5 + j);
  const float t3 = ((3==START_TAG)?0.f:NEGV) + __shfl(cur, 3*5 + j);
  const float t4 = ((4==START_TAG)?0.f:NEGV) + __shfl(cur, 4*5 + j);
  const float aF = lse5(t0,t1,t2,t3,t4);
  const float f0 = __shfl(aF, 0) + trans[STOP_TAG*NTAG + 0];
  const float f1 = __shfl(aF, 1) + trans[STOP_TAG*NTAG + 1];
  const float f2 = __shfl(aF, 2) + trans[STOP_TAG*NTAG + 2];
  const float f3 = __shfl(aF, 3) + trans[STOP_TAG*NTAG + 3];
  const float f4 = __shfl(aF, 4) + trans[STOP_TAG*NTAG + 4];
  const float fwd = lse5(f0,f1,f2,f3,f4);
  float gv = gold_part[l];
#pragma unroll
  for (int off = 32; off; off >>= 1) gv += __shfl_xor(gv, off);
  if (l == 0) out[0] = fwd - (gv + trans[STOP_TAG*NTAG + tags[S_LEN-1]]);
}

// ---------- launcher ----------
extern "C" void kernel_launch(void* const* d_in, const int* in_sizes, int n_in,
                              void* d_out, int out_size, void* d_ws, size_t ws_size,
                              hipStream_t stream) {
  const int*   sentence = (const int*)d_in[0];
  const int*   tags     = (const int*)d_in[1];
  const float* emb      = (const float*)d_in[2];
  const float* w_ih_f   = (const float*)d_in[3];
  const float* w_hh_f   = (const float*)d_in[4];
  const float* b_ih_f   = (const float*)d_in[5];
  const float* b_hh_f   = (const float*)d_in[6];
  const float* w_ih_b   = (const float*)d_in[7];
  const float* w_hh_b   = (const float*)d_in[8];
  const float* b_ih_b   = (const float*)d_in[9];
  const float* b_hh_b   = (const float*)d_in[10];
  const float* w_tag    = (const float*)d_in[11];
  const float* b_tag    = (const float*)d_in[12];
  const float* trans    = (const float*)d_in[13];
  float* out = (float*)d_out;
  char* ws = (char*)d_ws;
  if (ws_size < WS_NEEDED) return;

  __hip_bfloat16* xp    = (__hip_bfloat16*)(ws + OFF_XP);
  unsigned short* hpub  = (unsigned short*)(ws + OFF_HBS);
  float* feats          = (float*)(ws + OFF_FEATS);
  float* Mpart          = (float*)(ws + OFF_MPART);
  float* gold_part      = (float*)(ws + OFF_GOLD);

  const int n4 = (2 * S_LEN * HP_ROW * 2) / 16;   // bf16 publication bytes / 16
  fill_poison<<<dim3(1024), dim3(256), 0, stream>>>((float*)hpub, n4);
  xp_gemm<<<dim3(512, 2, 1), dim3(256), 0, stream>>>(sentence, emb,
      w_ih_f, b_ih_f, b_hh_f, w_ih_b, b_ih_b, b_hh_b, xp);
  lstm_pers<<<dim3(256), dim3(256), 65536, stream>>>(w_hh_f, w_hh_b, xp, hpub);
  feats_ker<<<dim3(4096), dim3(64), 0, stream>>>(hpub, w_tag, b_tag, feats);
  crf_part<<<dim3(64), dim3(64), 0, stream>>>(feats, trans, tags, Mpart, gold_part);
  crf_final<<<dim3(1), dim3(64), 0, stream>>>(Mpart, gold_part, trans, tags, out);
}

// Round 8
// 24952.393 us; speedup vs baseline: 1.1028x; 1.1028x over previous
//
#include <hip/hip_runtime.h>
#include <hip/hip_bf16.h>

#define S_LEN 4096
#define EDIM  300
#define HDIM  512
#define G4    2048
#define NTAG  5
#define NEGV  -10000.0f
#define START_TAG 3
#define STOP_TAG  4
#define L2E 1.4426950408889634f
#define LN2 0.6931471805599453f
#define POIS_U 0x7F7F7F7Fu
#define HP_ROW 512   // bf16 elements per (dir,step) h row

typedef __attribute__((ext_vector_type(4))) float f32x4;
typedef __attribute__((ext_vector_type(4))) unsigned int u32x4;
typedef __attribute__((ext_vector_type(2))) unsigned int u32x2;

// ---------- workspace layout (bytes) ----------
static constexpr size_t OFF_XP    = 0;                                   // bf16 [2][S][2048]
static constexpr size_t XP_BYTES  = (size_t)2 * S_LEN * G4 * 2;
static constexpr size_t OFF_HBS   = OFF_XP + XP_BYTES;                   // bf16 [2][S][512] h publication
static constexpr size_t HBS_BYTES = (size_t)2 * S_LEN * HDIM * 4;       // region reserved (f32-era size)
static constexpr size_t OFF_FEATS = OFF_HBS + HBS_BYTES;                 // f32 [S][5]
static constexpr size_t OFF_MPART = OFF_FEATS + (size_t)S_LEN * NTAG * 4;// f32 [64][25]
static constexpr size_t OFF_GOLD  = OFF_MPART + (size_t)64 * 25 * 4;     // f32 [64]
static constexpr size_t OFF_SYNC  = OFF_GOLD + 256;                      // int tokens[64] + verd[64]
static constexpr size_t WS_NEEDED = OFF_SYNC + 1024;

// ---------- helpers ----------
static __device__ __forceinline__ float fexp_(float x){ return __builtin_amdgcn_exp2f(x * L2E); }
static __device__ __forceinline__ float fsig_(float x){ return __builtin_amdgcn_rcpf(1.0f + fexp_(-x)); }
static __device__ __forceinline__ float ftanh_(float x){ return 1.0f - 2.0f*__builtin_amdgcn_rcpf(fexp_(2.0f*x) + 1.0f); }

static __device__ __forceinline__ float lse5(float t0,float t1,float t2,float t3,float t4){
  float m = fmaxf(fmaxf(fmaxf(t0,t1),fmaxf(t2,t3)),t4);
  float s = __builtin_amdgcn_exp2f((t0-m)*L2E) + __builtin_amdgcn_exp2f((t1-m)*L2E)
          + __builtin_amdgcn_exp2f((t2-m)*L2E) + __builtin_amdgcn_exp2f((t3-m)*L2E)
          + __builtin_amdgcn_exp2f((t4-m)*L2E);
  return m + __builtin_amdgcn_logf(s)*LN2;
}

// C[i][j] = LSE_k(cur[i][k] + bv[k][j]); lane layout: lane = i*5+j (lanes 0..24)
static __device__ __forceinline__ float lse_mm(float cur, float bv, int i, int j){
  const float a0=__shfl(cur, i*5+0), a1=__shfl(cur, i*5+1), a2=__shfl(cur, i*5+2),
              a3=__shfl(cur, i*5+3), a4=__shfl(cur, i*5+4);
  const float c0=__shfl(bv, 0+j),  c1=__shfl(bv, 5+j),  c2=__shfl(bv, 10+j),
              c3=__shfl(bv, 15+j), c4=__shfl(bv, 20+j);
  return lse5(a0+c0, a1+c1, a2+c2, a3+c3, a4+c4);
}

// ---------- phase 0: poison-fill h publication buffer (coherent stores) ----------
__global__ __launch_bounds__(256) void fill_poison(float* __restrict__ p, int n4){
  const int idx = blockIdx.x*blockDim.x + threadIdx.x;
  const int stride = gridDim.x*blockDim.x;
  f32x4 pv;
  pv.x = __uint_as_float(POIS_U); pv.y = __uint_as_float(POIS_U);
  pv.z = __uint_as_float(POIS_U); pv.w = __uint_as_float(POIS_U);
  for (int i = idx; i < n4; i += stride) {
    float* dst = p + (size_t)i*4;
    asm volatile("global_store_dwordx4 %0, %1, off sc0 sc1" :: "v"(dst), "v"(pv) : "memory");
  }
}

// ---------- phase A: xp[dir][s][2048] = emb[sent[s]] @ w_ih.T + (b_ih+b_hh), stored bf16 ----------
__global__ __launch_bounds__(256) void xp_gemm(
    const int* __restrict__ sentence, const float* __restrict__ emb,
    const float* __restrict__ w_ih_f, const float* __restrict__ b_ih_f, const float* __restrict__ b_hh_f,
    const float* __restrict__ w_ih_b, const float* __restrict__ b_ih_b, const float* __restrict__ b_hh_b,
    __hip_bfloat16* __restrict__ xp)
{
  __shared__ float At[32][132];
  __shared__ float Bt[32][132];
  __shared__ int sent_s[128];

  const int dir = blockIdx.y;
  const int tm = blockIdx.x & 31;
  const int tn = blockIdx.x >> 5;
  const float* __restrict__ wih = dir ? w_ih_b : w_ih_f;
  const float* __restrict__ bi  = dir ? b_ih_b : b_ih_f;
  const float* __restrict__ bh  = dir ? b_hh_b : b_hh_f;

  const int tid = threadIdx.x;
  if (tid < 128) sent_s[tid] = sentence[tm*128 + tid];

  const int ty = tid >> 4, tx = tid & 15;
  const int li = tid >> 1, lh = tid & 1;

  float acc[8][8];
#pragma unroll
  for (int i = 0; i < 8; ++i){
#pragma unroll
    for (int j = 0; j < 8; ++j) acc[i][j] = 0.0f;
  }
  __syncthreads();

  for (int kc0 = 0; kc0 < EDIM; kc0 += 32) {
    const int kw = (EDIM - kc0 < 32) ? (EDIM - kc0) : 32;
    if (kc0 + lh*16 + 16 <= EDIM) {
      const float4* pa = (const float4*)(emb + (size_t)sent_s[li]*EDIM + kc0 + lh*16);
      const float4* pb = (const float4*)(wih + (size_t)(tn*128 + li)*EDIM + kc0 + lh*16);
#pragma unroll
      for (int v = 0; v < 4; ++v) {
        const float4 a = pa[v], b = pb[v];
        const int kk = lh*16 + v*4;
        At[kk+0][li] = a.x; At[kk+1][li] = a.y; At[kk+2][li] = a.z; At[kk+3][li] = a.w;
        Bt[kk+0][li] = b.x; Bt[kk+1][li] = b.y; Bt[kk+2][li] = b.z; Bt[kk+3][li] = b.w;
      }
    } else {
#pragma unroll
      for (int jj = 0; jj < 16; ++jj) {
        const int col = kc0 + lh*16 + jj;
        float av = 0.f, bv = 0.f;
        if (col < EDIM) {
          av = emb[(size_t)sent_s[li]*EDIM + col];
          bv = wih[(size_t)(tn*128 + li)*EDIM + col];
        }
        At[lh*16+jj][li] = av;
        Bt[lh*16+jj][li] = bv;
      }
    }
    __syncthreads();
#pragma unroll 4
    for (int k = 0; k < kw; ++k) {
      const float4 a0 = *(const float4*)&At[k][ty*8];
      const float4 a1 = *(const float4*)&At[k][ty*8+4];
      const float4 b0 = *(const float4*)&Bt[k][tx*8];
      const float4 b1 = *(const float4*)&Bt[k][tx*8+4];
      const float av[8] = {a0.x,a0.y,a0.z,a0.w,a1.x,a1.y,a1.z,a1.w};
      const float bv[8] = {b0.x,b0.y,b0.z,b0.w,b1.x,b1.y,b1.z,b1.w};
#pragma unroll
      for (int i = 0; i < 8; ++i){
#pragma unroll
        for (int j = 0; j < 8; ++j) acc[i][j] = __builtin_fmaf(av[i], bv[j], acc[i][j]);
      }
    }
    __syncthreads();
  }

  const int n0 = tn*128 + tx*8;
  float bias[8];
#pragma unroll
  for (int j = 0; j < 8; ++j) bias[j] = bi[n0+j] + bh[n0+j];

  __hip_bfloat16* __restrict__ xpd = xp + (size_t)dir * S_LEN * G4;
#pragma unroll
  for (int i = 0; i < 8; ++i) {
    const int m = tm*128 + ty*8 + i;
    __hip_bfloat16 __align__(16) tmp[8];
#pragma unroll
    for (int j = 0; j < 8; ++j) tmp[j] = __float2bfloat16(acc[i][j] + bias[j]);
    *(uint4*)(xpd + (size_t)m*G4 + n0) = *(const uint4*)tmp;
  }
}

// ---------- phase B: persistent BiLSTM — bf16 W in LDS, ELECTED single-scope sync ----------
// 256 blocks; b%8==0 -> forward role b>>3 (32 roles), b%8==1 -> backward, others exit.
// If blockIdx%8 == XCD (round-robin), each direction's 32 wgs share ONE physical L2 -> sc0
// store/poll is a local hit-update (~250 cyc RT). Runtime election verifies this with sc0
// tokens + timeout; verdicts are exchanged via reliable sc0sc1 and ANDed -> unanimous choice
// of fast (sc0-only) or slow (sc0sc1, R2-proven) protocol. Math identical either way.
// Per wg: 16 units, W slice 64 rows x 512 bf16 in 64 KB LDS. 4 waves x 4 units (R2/R7 core).
__global__ __launch_bounds__(256, 1) void lstm_pers(
    const float* __restrict__ w_hh_f, const float* __restrict__ w_hh_b,
    const __hip_bfloat16* __restrict__ xp, unsigned short* __restrict__ hpub,
    int* __restrict__ syncp)
{
  extern __shared__ unsigned int Wl[];   // [64][256] u32 = 64 rows x 512 bf16 = 64 KB
  __shared__ int fast_sh;

  const int b = blockIdx.x;
  const int slot = b & 7;
  if (slot >= 2) return;                 // 192 loser blocks exit immediately
  const int dir  = slot;
  const int role = b >> 3;               // 0..31

  const int tid = threadIdx.x;
  const int w_  = tid >> 6;              // wave 0..3
  const int l   = tid & 63;
  const int u   = l & 3;                 // unit tracked by this lane's gate path
  const int gu  = role*16 + w_*4 + u;    // global unit

  const float* __restrict__ whh = dir ? w_hh_b : w_hh_f;
  const __hip_bfloat16* __restrict__ xpd = xp + (size_t)dir * S_LEN * G4;
  unsigned short* __restrict__ hp = hpub + (size_t)dir * S_LEN * HP_ROW;

  // ---- stage W slice to LDS as bf16 (R7-verified layout)
  {
    const int R = tid >> 2, q = tid & 3;           // thread covers row R, f32 cols [q*128, q*128+128)
    const int g = R & 3, ul = (R >> 2) & 3, wv = R >> 4;
    const float* src = whh + (size_t)(g*HDIM + role*16 + wv*4 + ul)*HDIM + q*128;
    unsigned int* dst = Wl + R*256 + q*64;         // 64 u32 = 128 bf16
#pragma unroll
    for (int k = 0; k < 128; k += 8) {
      const f32x4 f0 = *(const f32x4*)(src + k);
      const f32x4 f1 = *(const f32x4*)(src + k + 4);
      u32x4 pk;
      pk.x = (unsigned int)__builtin_bit_cast(unsigned short, __float2bfloat16(f0.x))
           | ((unsigned int)__builtin_bit_cast(unsigned short, __float2bfloat16(f0.y)) << 16);
      pk.y = (unsigned int)__builtin_bit_cast(unsigned short, __float2bfloat16(f0.z))
           | ((unsigned int)__builtin_bit_cast(unsigned short, __float2bfloat16(f0.w)) << 16);
      pk.z = (unsigned int)__builtin_bit_cast(unsigned short, __float2bfloat16(f1.x))
           | ((unsigned int)__builtin_bit_cast(unsigned short, __float2bfloat16(f1.y)) << 16);
      pk.w = (unsigned int)__builtin_bit_cast(unsigned short, __float2bfloat16(f1.z))
           | ((unsigned int)__builtin_bit_cast(unsigned short, __float2bfloat16(f1.w)) << 16);
      *(u32x4*)(dst + k/2) = pk;
    }
  }
  __syncthreads();

  // ---- visibility election (wave 0): sc0 tokens + timeout, sc0sc1 verdict AND
  if (w_ == 0) {
    int* tok = syncp + dir*32;          // tokens, own cache lines per dir
    int* vrd = syncp + 64 + dir*32;     // verdicts
    if (l == 0) {
      const int one = 1;
      asm volatile("global_store_dword %0, %1, off sc0" :: "v"(tok + role), "v"(one));
    }
    int seen = 0;
    for (int it = 0; it < 4096 && !seen; ++it) {
      int tv = 1;
      if (l < 32) {
        asm volatile("global_load_dword %0, %1, off sc0\n\ts_waitcnt vmcnt(0)"
                     : "=v"(tv) : "v"(tok + l));
      }
      seen = __all(tv == 1) ? 1 : 0;
      if (!seen) __builtin_amdgcn_s_sleep(2);
    }
    if (l == 0) {
      asm volatile("global_store_dword %0, %1, off sc0 sc1" :: "v"(vrd + role), "v"(seen));
    }
    int vv = 0;
    while (true) {
      int t = 1;
      if (l < 32) {
        asm volatile("global_load_dword %0, %1, off sc0 sc1\n\ts_waitcnt vmcnt(0)"
                     : "=v"(t) : "v"(vrd + l));
      }
      if (__all(t != -1)) { vv = __all(t == 1) ? 1 : 0; break; }
      __builtin_amdgcn_s_sleep(8);
    }
    if (l == 0) fast_sh = vv;
  }
  __syncthreads();
  const bool fast = fast_sh != 0;

  const unsigned int* wrow = Wl + (size_t)(w_*16)*256 + l*4;  // row r at wrow + r*256 (u32x4 = 8 bf16 cols)

  const __hip_bfloat16* xptr = xpd + (size_t)(dir ? (S_LEN-1) : 0)*G4 + gu;
  const ptrdiff_t xstep = dir ? -(ptrdiff_t)G4 : (ptrdiff_t)G4;
  float xn0 = __bfloat162float(xptr[0*HDIM]);
  float xn1 = __bfloat162float(xptr[1*HDIM]);
  float xn2 = __bfloat162float(xptr[2*HDIM]);
  float xn3 = __bfloat162float(xptr[3*HDIM]);

  // gather lane for row r=4u+g sits at lane f_ pattern (R2-verified mapping)
  const int f_ = 2*(l&1) + ((l>>1)&1);
  float cst = 0.0f;

  // ---- step 0: h_{-1}=0, gates from xp only; publish
  {
    const float iv = fsig_(xn0), fv = fsig_(xn1), zv = ftanh_(xn2), ov = fsig_(xn3);
    cst = iv*zv;
    const float hval = ov * ftanh_(cst);
    const unsigned int hb = (unsigned int)__builtin_bit_cast(unsigned short, __float2bfloat16(hval));
    u32x2 g2;
    g2.x = __shfl(hb, 0) | (__shfl(hb, 1) << 16);
    g2.y = __shfl(hb, 2) | (__shfl(hb, 3) << 16);
    if (l == 0) {
      unsigned short* dp = hp + (size_t)0*HP_ROW + role*16 + w_*4;
      if (fast) asm volatile("global_store_dwordx2 %0, %1, off sc0"     :: "v"(dp), "v"(g2));
      else      asm volatile("global_store_dwordx2 %0, %1, off sc0 sc1" :: "v"(dp), "v"(g2));
    }
    xptr += xstep;
    xn0 = __bfloat162float(xptr[0*HDIM]);
    xn1 = __bfloat162float(xptr[1*HDIM]);
    xn2 = __bfloat162float(xptr[2*HDIM]);
    xn3 = __bfloat162float(xptr[3*HDIM]);
  }

#pragma clang loop unroll(disable)
  for (int s = 1; s < S_LEN; ++s) {
    // 1. poll h_{s-1}: lane l covers bf16 units [8l, 8l+8) = 16 B. Single load per iteration,
    //    scope chosen by the election (fast: local-L2 sc0; slow: IF$ sc0sc1, R2-proven).
    u32x4 pa;
    {
      const unsigned short* sp = hp + (size_t)(s-1)*HP_ROW + l*8;
      if (fast) {
        for (int it = 0; it < (1<<18); ++it) {
          asm volatile("global_load_dwordx4 %0, %1, off sc0\n\ts_waitcnt vmcnt(0)"
                       : "=&v"(pa) : "v"(sp));
          if (__all((pa.x != POIS_U) & (pa.y != POIS_U) & (pa.z != POIS_U) & (pa.w != POIS_U))) break;
        }
      } else {
        for (int it = 0; it < (1<<16); ++it) {
          asm volatile("global_load_dwordx4 %0, %1, off sc0 sc1\n\ts_waitcnt vmcnt(0)"
                       : "=&v"(pa) : "v"(sp));
          if (__all((pa.x != POIS_U) & (pa.y != POIS_U) & (pa.z != POIS_U) & (pa.w != POIS_U))) break;
        }
      }
    }

    // 2. matvec: 16 gate rows x 8 cols, W unpacked from LDS bf16 (R7-verified)
    float acc[16];
    {
      const float h0 = __uint_as_float(pa.x << 16), h1 = __uint_as_float(pa.x & 0xFFFF0000u);
      const float h2 = __uint_as_float(pa.y << 16), h3 = __uint_as_float(pa.y & 0xFFFF0000u);
      const float h4 = __uint_as_float(pa.z << 16), h5 = __uint_as_float(pa.z & 0xFFFF0000u);
      const float h6 = __uint_as_float(pa.w << 16), h7 = __uint_as_float(pa.w & 0xFFFF0000u);
#pragma unroll
      for (int r = 0; r < 16; ++r) {
        const u32x4 wv4 = *(const u32x4*)(wrow + r*256);
        float a =            __uint_as_float(wv4.x << 16)        * h0;
        a = __builtin_fmaf(__uint_as_float(wv4.x & 0xFFFF0000u), h1, a);
        a = __builtin_fmaf(__uint_as_float(wv4.y << 16),         h2, a);
        a = __builtin_fmaf(__uint_as_float(wv4.y & 0xFFFF0000u), h3, a);
        a = __builtin_fmaf(__uint_as_float(wv4.z << 16),         h4, a);
        a = __builtin_fmaf(__uint_as_float(wv4.z & 0xFFFF0000u), h5, a);
        a = __builtin_fmaf(__uint_as_float(wv4.w << 16),         h6, a);
        a = __builtin_fmaf(__uint_as_float(wv4.w & 0xFFFF0000u), h7, a);
        acc[r] = a;
      }
    }

    // 3. reduce-scatter 16 row-partials over 64 lanes (R2-verified)
#pragma unroll
    for (int k = 0; k < 4; ++k) {
      const int m = 1 << k;
      const int half = 8 >> k;
      const bool up = (l & m) != 0;
#pragma unroll
      for (int t = 0; t < half; ++t) {
        const float mine = up ? acc[half+t] : acc[t];
        const float send = up ? acc[t] : acc[half+t];
        acc[t] = mine + __shfl_xor(send, m);
      }
    }
    float tot = acc[0];
    tot += __shfl_xor(tot, 16);
    tot += __shfl_xor(tot, 32);

    // 4. gates for unit u = l&3 (all lanes redundant; R2-verified gather); publish
    {
      const float gi = __shfl(tot, f_ + 0)  + xn0;
      const float gf = __shfl(tot, f_ + 8)  + xn1;
      const float gg = __shfl(tot, f_ + 4)  + xn2;
      const float go = __shfl(tot, f_ + 12) + xn3;
      const float iv = fsig_(gi), fv = fsig_(gf), zv = ftanh_(gg), ov = fsig_(go);
      cst = fv*cst + iv*zv;
      const float hval = ov * ftanh_(cst);
      const unsigned int hb = (unsigned int)__builtin_bit_cast(unsigned short, __float2bfloat16(hval));
      u32x2 g2;
      g2.x = __shfl(hb, 0) | (__shfl(hb, 1) << 16);
      g2.y = __shfl(hb, 2) | (__shfl(hb, 3) << 16);
      if (l == 0) {
        unsigned short* dp = hp + (size_t)s*HP_ROW + role*16 + w_*4;
        if (fast) asm volatile("global_store_dwordx2 %0, %1, off sc0"     :: "v"(dp), "v"(g2));
        else      asm volatile("global_store_dwordx2 %0, %1, off sc0 sc1" :: "v"(dp), "v"(g2));
      }
    }

    // 5. prefetch next step's xp gate values (off the critical path)
    if (s + 1 < S_LEN) {
      xptr += xstep;
      xn0 = __bfloat162float(xptr[0*HDIM]);
      xn1 = __bfloat162float(xptr[1*HDIM]);
      xn2 = __bfloat162float(xptr[2*HDIM]);
      xn3 = __bfloat162float(xptr[3*HDIM]);
    }
  }
}

// ---------- phase C: feats[s][t] = [hf,hb] . w_tag[t] + b_tag[t] (h is bf16) ----------
__global__ __launch_bounds__(64) void feats_ker(
    const unsigned short* __restrict__ hpub, const float* __restrict__ w_tag,
    const float* __restrict__ b_tag, float* __restrict__ feats)
{
  const int row = blockIdx.x;
  const int l = threadIdx.x;
  const u32x4 hfv4 = *(const u32x4*)(hpub + (size_t)row*HP_ROW + l*8);
  const u32x4 hbv4 = *(const u32x4*)(hpub + (size_t)S_LEN*HP_ROW + (size_t)(S_LEN-1-row)*HP_ROW + l*8);
  float hf[8], hb[8];
  hf[0]=__uint_as_float(hfv4.x<<16); hf[1]=__uint_as_float(hfv4.x&0xFFFF0000u);
  hf[2]=__uint_as_float(hfv4.y<<16); hf[3]=__uint_as_float(hfv4.y&0xFFFF0000u);
  hf[4]=__uint_as_float(hfv4.z<<16); hf[5]=__uint_as_float(hfv4.z&0xFFFF0000u);
  hf[6]=__uint_as_float(hfv4.w<<16); hf[7]=__uint_as_float(hfv4.w&0xFFFF0000u);
  hb[0]=__uint_as_float(hbv4.x<<16); hb[1]=__uint_as_float(hbv4.x&0xFFFF0000u);
  hb[2]=__uint_as_float(hbv4.y<<16); hb[3]=__uint_as_float(hbv4.y&0xFFFF0000u);
  hb[4]=__uint_as_float(hbv4.z<<16); hb[5]=__uint_as_float(hbv4.z&0xFFFF0000u);
  hb[6]=__uint_as_float(hbv4.w<<16); hb[7]=__uint_as_float(hbv4.w&0xFFFF0000u);

  float a[5];
#pragma unroll
  for (int t = 0; t < 5; ++t) {
    const float* wt = w_tag + t*1024 + l*8;
    const float* wb = w_tag + t*1024 + 512 + l*8;
    float s = 0.f;
#pragma unroll
    for (int k = 0; k < 8; ++k) s = __builtin_fmaf(hf[k], wt[k], s);
#pragma unroll
    for (int k = 0; k < 8; ++k) s = __builtin_fmaf(hb[k], wb[k], s);
    a[t] = s;
  }
#pragma unroll
  for (int off = 32; off; off >>= 1) {
    a[0] += __shfl_xor(a[0], off); a[1] += __shfl_xor(a[1], off); a[2] += __shfl_xor(a[2], off);
    a[3] += __shfl_xor(a[3], off); a[4] += __shfl_xor(a[4], off);
  }
  if (l == 0) {
#pragma unroll
    for (int t = 0; t < 5; ++t) feats[row*NTAG+t] = a[t] + b_tag[t];
  }
}

// ---------- phase D: CRF log-partition + gold score ----------
__global__ __launch_bounds__(64) void crf_part(
    const float* __restrict__ feats, const float* __restrict__ trans,
    const int* __restrict__ tags, float* __restrict__ Mpart, float* __restrict__ gold_part)
{
  const int blk = blockIdx.x;
  const int l = threadIdx.x;
  const int s0 = blk * 64;
  const bool act = (l < 25);
  const int i = act ? (l/5) : 0;
  const int j = act ? (l%5) : 0;
  const float tT = trans[j*NTAG + i];
  float cur = tT + feats[(size_t)s0*NTAG + j];
  for (int s = s0+1; s < s0+64; ++s) {
    const float bv = tT + feats[(size_t)s*NTAG + j];
    cur = lse_mm(cur, bv, i, j);
  }
  if (act) Mpart[blk*25 + l] = cur;

  const int s = s0 + l;
  const int tg = tags[s];
  const int pv = (s == 0) ? START_TAG : tags[s-1];
  float gv = trans[tg*NTAG + pv] + feats[(size_t)s*NTAG + tg];
#pragma unroll
  for (int off = 32; off; off >>= 1) gv += __shfl_xor(gv, off);
  if (l == 0) gold_part[blk] = gv;
}

__global__ __launch_bounds__(64) void crf_final(
    const float* __restrict__ Mpart, const float* __restrict__ gold_part,
    const float* __restrict__ trans, const int* __restrict__ tags, float* __restrict__ out)
{
  const int l = threadIdx.x;
  const bool act = (l < 25);
  const int i = act ? (l/5) : 0;
  const int j = act ? (l%5) : 0;
  float cur = Mpart[act ? l : 0];
  for (int b = 1; b < 64; ++b) {
    const float bv = Mpart[b*25 + (act ? l : 0)];
    cur = lse_mm(cur, bv, i, j);
  }
  const float t0 = ((0==START_TAG)?0.f:NEGV) + __shfl(cur, 0*5 + j);
  const float t1 = ((1==START_TAG)?0.f:NEGV) + __shfl(cur, 1*5 + j);
  const float t2 = ((2==START_TAG)?0.f:NEGV) + __shfl(cur, 2*5 + j);
  const float t3 = ((3==START_TAG)?0.f:NEGV) + __shfl(cur, 3*5 + j);
  const float t4 = ((4==START_TAG)?0.f:NEGV) + __shfl(cur, 4*5 + j);
  const float aF = lse5(t0,t1,t2,t3,t4);
  const float f0 = __shfl(aF, 0) + trans[STOP_TAG*NTAG + 0];
  const float f1 = __shfl(aF, 1) + trans[STOP_TAG*NTAG + 1];
  const float f2 = __shfl(aF, 2) + trans[STOP_TAG*NTAG + 2];
  const float f3 = __shfl(aF, 3) + trans[STOP_TAG*NTAG + 3];
  const float f4 = __shfl(aF, 4) + trans[STOP_TAG*NTAG + 4];
  const float fwd = lse5(f0,f1,f2,f3,f4);
  float gv = gold_part[l];
#pragma unroll
  for (int off = 32; off; off >>= 1) gv += __shfl_xor(gv, off);
  if (l == 0) out[0] = fwd - (gv + trans[STOP_TAG*NTAG + tags[S_LEN-1]]);
}

// ---------- launcher ----------
extern "C" void kernel_launch(void* const* d_in, const int* in_sizes, int n_in,
                              void* d_out, int out_size, void* d_ws, size_t ws_size,
                              hipStream_t stream) {
  const int*   sentence = (const int*)d_in[0];
  const int*   tags     = (const int*)d_in[1];
  const float* emb      = (const float*)d_in[2];
  const float* w_ih_f   = (const float*)d_in[3];
  const float* w_hh_f   = (const float*)d_in[4];
  const float* b_ih_f   = (const float*)d_in[5];
  const float* b_hh_f   = (const float*)d_in[6];
  const float* w_ih_b   = (const float*)d_in[7];
  const float* w_hh_b   = (const float*)d_in[8];
  const float* b_ih_b   = (const float*)d_in[9];
  const float* b_hh_b   = (const float*)d_in[10];
  const float* w_tag    = (const float*)d_in[11];
  const float* b_tag    = (const float*)d_in[12];
  const float* trans    = (const float*)d_in[13];
  float* out = (float*)d_out;
  char* ws = (char*)d_ws;
  if (ws_size < WS_NEEDED) return;

  __hip_bfloat16* xp    = (__hip_bfloat16*)(ws + OFF_XP);
  unsigned short* hpub  = (unsigned short*)(ws + OFF_HBS);
  float* feats          = (float*)(ws + OFF_FEATS);
  float* Mpart          = (float*)(ws + OFF_MPART);
  float* gold_part      = (float*)(ws + OFF_GOLD);
  int*   syncp          = (int*)(ws + OFF_SYNC);

  hipMemsetAsync(ws + OFF_SYNC, 0xFF, 1024, stream);   // tokens/verdicts = -1
  const int n4 = (2 * S_LEN * HP_ROW * 2) / 16;        // bf16 publication bytes / 16
  fill_poison<<<dim3(1024), dim3(256), 0, stream>>>((float*)hpub, n4);
  xp_gemm<<<dim3(512, 2, 1), dim3(256), 0, stream>>>(sentence, emb,
      w_ih_f, b_ih_f, b_hh_f, w_ih_b, b_ih_b, b_hh_b, xp);
  lstm_pers<<<dim3(256), dim3(256), 65536, stream>>>(w_hh_f, w_hh_b, xp, hpub, syncp);
  feats_ker<<<dim3(4096), dim3(64), 0, stream>>>(hpub, w_tag, b_tag, feats);
  crf_part<<<dim3(64), dim3(64), 0, stream>>>(feats, trans, tags, Mpart, gold_part);
  crf_final<<<dim3(1), dim3(64), 0, stream>>>(Mpart, gold_part, trans, tags, out);
}